// Round 4
// baseline (2068.344 us; speedup 1.0000x reference)
//
#include <hip/hip_runtime.h>
#include <hip/hip_bf16.h>
#include <math.h>

#define B_ 32
#define T_ 128
#define V_ 32000
#define D_ 512
#define H_ 512

typedef __attribute__((ext_vector_type(8))) short bf16x8;
typedef __attribute__((ext_vector_type(4))) float f32x4;

#define AS1 __attribute__((address_space(1)))
#define AS3 __attribute__((address_space(3)))

__device__ __forceinline__ unsigned short f2bf(float x) {
  unsigned int b = __float_as_uint(x);
  return (unsigned short)((b + 0x7FFFu + ((b >> 16) & 1u)) >> 16);
}
__device__ __forceinline__ float bf2f(unsigned short u) {
  return __uint_as_float(((unsigned int)u) << 16);
}
__device__ __forceinline__ float sigm(float x) { return 1.0f / (1.0f + expf(-x)); }

// ---------------- embedding gather -> bf16
__global__ __launch_bounds__(64) void embed_bf_kernel(const int* __restrict__ dst,
                                                      const float* __restrict__ E,
                                                      unsigned short* __restrict__ embbf) {
  int rt = blockIdx.x;           // t*32 + b
  int t = rt >> 5, b = rt & 31;
  int v = dst[b * T_ + t];
  const float4* src = (const float4*)(E + (size_t)v * D_);
  ushort4* d = (ushort4*)(embbf + (size_t)rt * D_);
  #pragma unroll
  for (int r = 0; r < 2; ++r) {
    float4 x = src[threadIdx.x + r * 64];
    ushort4 o; o.x = f2bf(x.x); o.y = f2bf(x.y); o.z = f2bf(x.z); o.w = f2bf(x.w);
    d[threadIdx.x + r * 64] = o;
  }
}

// ---------------- generic f32 -> bf16
__global__ void cvt_kernel(const float* __restrict__ in, unsigned short* __restrict__ out, int n4) {
  int stride = gridDim.x * blockDim.x;
  for (int i = blockIdx.x * blockDim.x + threadIdx.x; i < n4; i += stride) {
    float4 v = ((const float4*)in)[i];
    ushort4 o; o.x = f2bf(v.x); o.y = f2bf(v.y); o.z = f2bf(v.z); o.w = f2bf(v.w);
    ((ushort4*)out)[i] = o;
  }
}

// ---------------- W1bf[r][c] = bf16(Wih[r][c]), c<512 (row stride 1024)
__global__ void cvt_w1_kernel(const float* __restrict__ Wih, unsigned short* __restrict__ W1bf, int n4) {
  int stride = gridDim.x * blockDim.x;
  for (int i = blockIdx.x * blockDim.x + threadIdx.x; i < n4; i += stride) {
    int flat = i * 4;
    int r = flat >> 9, c = flat & 511;
    float4 v = *(const float4*)(Wih + (size_t)r * 1024 + c);
    ushort4 o; o.x = f2bf(v.x); o.y = f2bf(v.y); o.z = f2bf(v.z); o.w = f2bf(v.w);
    ((ushort4*)W1bf)[i] = o;
  }
}

// ---------------- Wrs[grow][chunk^(grow&7)] = bf16(Wih[grow][512+k] + Whh[grow][k])
__global__ void wr_prep_swz_kernel(const float* __restrict__ Wih, const float* __restrict__ Whh,
                                   unsigned short* __restrict__ Wrs, int n4) {
  int stride = gridDim.x * blockDim.x;
  for (int i = blockIdx.x * blockDim.x + threadIdx.x; i < n4; i += stride) {
    int flat = i * 4;
    int grow = flat >> 9, k = flat & 511;
    float4 a = *(const float4*)(Wih + (size_t)grow * 1024 + 512 + k);
    float4 b = ((const float4*)Whh)[i];
    ushort4 o;
    o.x = f2bf(a.x + b.x); o.y = f2bf(a.y + b.y); o.z = f2bf(a.z + b.z); o.w = f2bf(a.w + b.w);
    int chunk = (k >> 3) ^ (grow & 7);
    *(ushort4*)(Wrs + (size_t)grow * 512 + chunk * 8 + (k & 7)) = o;
  }
}

// ---------------- pre-GEMM: preA2[t][grow][b] = bf16(emb . W1 + bias)
__global__ __launch_bounds__(256) void gemm_pre_kernel(
    const unsigned short* __restrict__ A,
    const unsigned short* __restrict__ Bm,
    const float* __restrict__ bih, const float* __restrict__ bhh,
    unsigned short* __restrict__ preA2)
{
  __shared__ unsigned short ldsA[2][128 * 32];
  __shared__ unsigned short ldsB[2][128 * 32];
  const int tid = threadIdx.x;
  const int lane = tid & 63;
  const int wid = tid >> 6;
  const int wm = wid >> 1, wn = wid & 1;
  const int m0 = blockIdx.y * 128;
  const int n0 = blockIdx.x * 128;
  const int srow = lane >> 2;
  const int scol = (lane & 3) * 8;

  f32x4 acc[4][4] = {};
  const int NK = 512 / 32;

  auto stage = [&](int kk, int buf) {
    const int k0 = kk * 32;
    #pragma unroll
    for (int c = 0; c < 2; ++c) {
      const int r = wid * 32 + c * 16;
      const unsigned short* sa = A  + (size_t)(m0 + r + srow) * 512 + k0 + scol;
      const unsigned short* sb = Bm + (size_t)(n0 + r + srow) * 512 + k0 + scol;
      __builtin_amdgcn_global_load_lds((const AS1 void*)sa, (AS3 void*)&ldsA[buf][r * 32], 16, 0, 0);
      __builtin_amdgcn_global_load_lds((const AS1 void*)sb, (AS3 void*)&ldsB[buf][r * 32], 16, 0, 0);
    }
  };

  stage(0, 0);
  __syncthreads();

  const int rl = lane & 15;
  const int kb = lane >> 4;

  for (int kk = 0; kk < NK; ++kk) {
    const int buf = kk & 1;
    if (kk + 1 < NK) stage(kk + 1, buf ^ 1);
    const bf16x8* Af = (const bf16x8*)&ldsA[buf][0];
    const bf16x8* Bf = (const bf16x8*)&ldsB[buf][0];
    bf16x8 av[4], bv[4];
    #pragma unroll
    for (int mi = 0; mi < 4; ++mi) av[mi] = Af[(wm * 64 + mi * 16 + rl) * 4 + kb];
    #pragma unroll
    for (int ni = 0; ni < 4; ++ni) bv[ni] = Bf[(wn * 64 + ni * 16 + rl) * 4 + kb];
    #pragma unroll
    for (int mi = 0; mi < 4; ++mi)
      #pragma unroll
      for (int ni = 0; ni < 4; ++ni)
        acc[mi][ni] = __builtin_amdgcn_mfma_f32_16x16x32_bf16(av[mi], bv[ni], acc[mi][ni], 0, 0, 0);
    __syncthreads();
  }

  const int rb = (lane >> 4) * 4;
  #pragma unroll
  for (int mi = 0; mi < 4; ++mi)
    #pragma unroll
    for (int ni = 0; ni < 4; ++ni) {
      int mbase = m0 + wm * 64 + mi * 16 + rb;
      int col   = n0 + wn * 64 + ni * 16 + rl;
      float bb = bih[col] + bhh[col];
      ushort4 o;
      o.x = f2bf(acc[mi][ni][0] + bb); o.y = f2bf(acc[mi][ni][1] + bb);
      o.z = f2bf(acc[mi][ni][2] + bb); o.w = f2bf(acc[mi][ni][3] + bb);
      *(ushort4*)&preA2[((size_t)(mbase >> 5) * 2048 + col) * 32 + (mbase & 31)] = o;
    }
}

// ---------------- preA2[t=0][r][:] += (out0 - h0) @ W2^T
__global__ __launch_bounds__(256) void delta0_kernel(const float* __restrict__ Wih,
                                                     const float* __restrict__ out0,
                                                     const float* __restrict__ h0,
                                                     unsigned short* __restrict__ preA2) {
  const int r = blockIdx.x;
  const int tid = threadIdx.x;
  const int b = tid >> 3, seg = tid & 7;
  __shared__ float red[32][9];
  const float4* o4 = (const float4*)(out0 + (size_t)b * 512 + seg * 64);
  const float4* h4 = (const float4*)(h0 + (size_t)b * 512 + seg * 64);
  const float4* w4 = (const float4*)(Wih + (size_t)r * 1024 + 512 + seg * 64);
  float s = 0.f;
  #pragma unroll
  for (int j = 0; j < 16; ++j) {
    float4 o = o4[j], h = h4[j], w = w4[j];
    s += (o.x - h.x) * w.x + (o.y - h.y) * w.y + (o.z - h.z) * w.z + (o.w - h.w) * w.w;
  }
  red[b][seg] = s;
  __syncthreads();
  if (tid < 32) {
    float t = 0.f;
    #pragma unroll
    for (int j = 0; j < 8; ++j) t += red[tid][j];
    unsigned short* p = preA2 + (size_t)r * 32 + tid;
    *p = f2bf(bf2f(*p) + t);
  }
}

// ---------------- persistent LSTM: all 128 steps, one launch, 64 co-resident blocks
__global__ __launch_bounds__(256) void lstm_persist_kernel(
    const unsigned short* __restrict__ Wrs,   // [2048][512] bf16, chunk-swizzled rows
    const unsigned short* __restrict__ preA2, // [T][2048][32] bf16 (bias folded)
    const float* __restrict__ c0,             // [32][512] f32
    unsigned short* __restrict__ hA,          // [32][512] bf16 ping (holds h0 at start)
    unsigned short* __restrict__ hB,          // pong
    unsigned short* __restrict__ Abf,         // [B*T][512] bf16
    unsigned int* __restrict__ bar)           // zeroed each call
{
  __shared__ unsigned short wlds[32 * 512];   // 32 KB, resident across all steps
  __shared__ float gl[32][33];
  const int tid = threadIdx.x, bid = blockIdx.x;
  const int lane = tid & 63, wid = tid >> 6;

  // stage W once (pre-swizzled global source, linear LDS dest)
  #pragma unroll
  for (int it = 0; it < 8; ++it) {
    int r = it * 4 + wid;
    int grow = (r >> 3) * 512 + bid * 8 + (r & 7);
    const unsigned short* src = Wrs + (size_t)grow * 512 + lane * 8;
    __builtin_amdgcn_global_load_lds((const AS1 void*)src, (AS3 void*)&wlds[r * 512], 16, 0, 0);
  }

  // epilogue role: this thread owns (batch eb, k-slot ekg); c stays in a register
  const int eb = tid >> 3, ek = tid & 7;
  const int ekg = bid * 8 + ek;
  float c_reg = c0[(size_t)eb * 512 + ekg];

  const int rt = wid >> 1, bt = wid & 1;
  const int rl = lane & 15, q = lane >> 4;
  const int row = rt * 16 + rl;
  const char* wbase = (const char*)wlds + row * 1024;
  const int rx = (row & 7) << 4;
  const size_t hrow = (size_t)(bt * 16 + rl) * 512;

  __syncthreads();   // drains W staging

  for (int t = 0; t < T_; ++t) {
    const unsigned short* hin = (t & 1) ? hB : hA;
    unsigned short* hout = (t & 1) ? hA : hB;

    f32x4 acc = {}, acc2 = {};
    #pragma unroll
    for (int kk = 0; kk < 16; kk += 2) {
      int k0 = kk * 32 + q * 8;
      int k1 = k0 + 32;
      bf16x8 av0 = *(const bf16x8*)(wbase + ((k0 * 2) ^ rx));
      bf16x8 bv0 = *(const bf16x8*)(hin + hrow + k0);
      bf16x8 av1 = *(const bf16x8*)(wbase + ((k1 * 2) ^ rx));
      bf16x8 bv1 = *(const bf16x8*)(hin + hrow + k1);
      acc  = __builtin_amdgcn_mfma_f32_16x16x32_bf16(av0, bv0, acc, 0, 0, 0);
      acc2 = __builtin_amdgcn_mfma_f32_16x16x32_bf16(av1, bv1, acc2, 0, 0, 0);
    }
    #pragma unroll
    for (int j = 0; j < 4; ++j)
      gl[rt * 16 + q * 4 + j][bt * 16 + rl] = acc[j] + acc2[j];
    __syncthreads();

    {
      const size_t pbase = (size_t)t * (2048 * 32);
      float g0 = gl[0 * 8 + ek][eb] + bf2f(preA2[pbase + (size_t)(0 * 512 + ekg) * 32 + eb]);
      float g1 = gl[1 * 8 + ek][eb] + bf2f(preA2[pbase + (size_t)(1 * 512 + ekg) * 32 + eb]);
      float g2 = gl[2 * 8 + ek][eb] + bf2f(preA2[pbase + (size_t)(2 * 512 + ekg) * 32 + eb]);
      float g3 = gl[3 * 8 + ek][eb] + bf2f(preA2[pbase + (size_t)(3 * 512 + ekg) * 32 + eb]);
      float iv = sigm(g0), fv = sigm(g1), gv = tanhf(g2), ov = sigm(g3);
      float cn = fv * c_reg + iv * gv;
      c_reg = cn;
      float hn = ov * tanhf(cn);
      unsigned short hb = f2bf(hn);
      hout[(size_t)eb * 512 + ekg] = hb;
      Abf[((size_t)eb * T_ + t) * 512 + ekg] = hb;
    }
    __syncthreads();   // all stores of this block complete (vmcnt drained)

    if (t != T_ - 1) {
      if (tid == 0) {
        __threadfence();                                  // release: flush to coherence point
        __hip_atomic_fetch_add(bar, 1u, __ATOMIC_RELAXED, __HIP_MEMORY_SCOPE_AGENT);
        const unsigned want = 64u * (unsigned)(t + 1);
        while (__hip_atomic_load(bar, __ATOMIC_RELAXED, __HIP_MEMORY_SCOPE_AGENT) < want)
          __builtin_amdgcn_s_sleep(1);
      }
      __syncthreads();
      __threadfence();                                    // acquire: invalidate stale caches
    }
  }
}

// ---------------- B-panel-resident projection GEMM + softmax partials
// grid 250 blocks (one 128-col panel each), 512 threads (8 waves, wm2 x wn4).
__global__ __launch_bounds__(512) void gemm_bres_kernel(
    const unsigned short* __restrict__ A,    // [4096][512] bf16
    const unsigned short* __restrict__ Bm,   // [32000][512] bf16
    float* __restrict__ C,
    float* __restrict__ pmax, float* __restrict__ psum)
{
  __shared__ unsigned short ldsB[128 * 512];     // 128 KB, row-chunk XOR(row&7)
  __shared__ unsigned short ldsA[2][128 * 32];   // 16 KB, row-chunk XOR(row&3)
  __shared__ float smax[4][128];
  __shared__ float ssum4[4][128];
  const int tid = threadIdx.x;
  const int lane = tid & 63, wid = tid >> 6;
  const int wm = wid >> 2, wn = wid & 3;
  const int n0 = blockIdx.x * 128;
  const int rl = lane & 15, kb = lane >> 4;

  // ---- B panel once: row r, LDS chunk c <- global chunk c^(r&7)
  for (int it = 0; it < 16; ++it) {
    int r = it * 8 + wid;
    const unsigned short* src = Bm + (size_t)(n0 + r) * 512 + ((lane ^ (r & 7)) * 8);
    __builtin_amdgcn_global_load_lds((const AS1 void*)src, (AS3 void*)&ldsB[r * 512], 16, 0, 0);
  }

  // ---- A stage: s = mi*16 + kk; [128 rows][32 k] per chunk
  auto stageA = [&](int s, int buf) {
    int mi = s >> 4, kk = s & 15;
    int m0 = mi * 128;
    int r0 = wid * 16;
    int r = r0 + (lane >> 2);
    int ch = lane & 3;
    const unsigned short* src = A + (size_t)(m0 + r) * 512 + kk * 32 + ((ch ^ (r & 3)) * 8);
    __builtin_amdgcn_global_load_lds((const AS1 void*)src, (AS3 void*)&ldsA[buf][r0 * 32], 16, 0, 0);
  };

  stageA(0, 0);
  __syncthreads();

  f32x4 acc[4][2] = {};
  const int NS = 32 * 16;
  for (int s = 0; s < NS; ++s) {
    const int buf = s & 1;
    const int kk = s & 15;
    if (s + 1 < NS) stageA(s + 1, buf ^ 1);

    bf16x8 av[4], bv[2];
    #pragma unroll
    for (int x = 0; x < 4; ++x) {
      int arow = wm * 64 + x * 16 + rl;
      av[x] = *(const bf16x8*)&ldsA[buf][arow * 32 + ((kb ^ (arow & 3)) * 8)];
    }
    #pragma unroll
    for (int y = 0; y < 2; ++y) {
      int brow = wn * 32 + y * 16 + rl;
      int ch = kk * 4 + kb;
      bv[y] = *(const bf16x8*)&ldsB[brow * 512 + ((ch ^ (brow & 7)) * 8)];
    }
    #pragma unroll
    for (int x = 0; x < 4; ++x)
      #pragma unroll
      for (int y = 0; y < 2; ++y)
        acc[x][y] = __builtin_amdgcn_mfma_f32_16x16x32_bf16(av[x], bv[y], acc[x][y], 0, 0, 0);
    __syncthreads();

    if (kk == 15) {
      const int m0 = (s >> 4) * 128;
      // C write
      #pragma unroll
      for (int x = 0; x < 4; ++x)
        #pragma unroll
        for (int y = 0; y < 2; ++y) {
          size_t rrow = (size_t)(m0 + wm * 64 + x * 16 + kb * 4);
          size_t col = (size_t)(n0 + wn * 32 + y * 16 + rl);
          #pragma unroll
          for (int j = 0; j < 4; ++j)
            C[(rrow + j) * (size_t)V_ + col] = acc[x][y][j];
        }
      // row-max partials (within this wave's 32 cols)
      #pragma unroll
      for (int x = 0; x < 4; ++x)
        #pragma unroll
        for (int j = 0; j < 4; ++j) {
          float m = fmaxf(acc[x][0][j], acc[x][1][j]);
          m = fmaxf(m, __shfl_xor(m, 1)); m = fmaxf(m, __shfl_xor(m, 2));
          m = fmaxf(m, __shfl_xor(m, 4)); m = fmaxf(m, __shfl_xor(m, 8));
          if (rl == 0) smax[wn][wm * 64 + x * 16 + kb * 4 + j] = m;
        }
      __syncthreads();
      #pragma unroll
      for (int x = 0; x < 4; ++x)
        #pragma unroll
        for (int j = 0; j < 4; ++j) {
          int rowl = wm * 64 + x * 16 + kb * 4 + j;
          float M = fmaxf(fmaxf(smax[0][rowl], smax[1][rowl]),
                          fmaxf(smax[2][rowl], smax[3][rowl]));
          float sv = __expf(acc[x][0][j] - M) + __expf(acc[x][1][j] - M);
          sv += __shfl_xor(sv, 1); sv += __shfl_xor(sv, 2);
          sv += __shfl_xor(sv, 4); sv += __shfl_xor(sv, 8);
          if (rl == 0) ssum4[wn][rowl] = sv;
        }
      __syncthreads();
      if (tid < 128) {
        float M = fmaxf(fmaxf(smax[0][tid], smax[1][tid]),
                        fmaxf(smax[2][tid], smax[3][tid]));
        float S = ssum4[0][tid] + ssum4[1][tid] + ssum4[2][tid] + ssum4[3][tid];
        pmax[(size_t)(m0 + tid) * 256 + blockIdx.x] = M;
        psum[(size_t)(m0 + tid) * 256 + blockIdx.x] = S;
      }
      #pragma unroll
      for (int x = 0; x < 4; ++x)
        #pragma unroll
        for (int y = 0; y < 2; ++y)
          acc[x][y] = (f32x4){0.f, 0.f, 0.f, 0.f};
    }
  }
}

// ---------------- finish: lse from partials, then C[row] -= lse
__global__ __launch_bounds__(256) void softmax_finish_kernel(
    float* __restrict__ C, const float* __restrict__ pmax, const float* __restrict__ psum) {
  const size_t row = blockIdx.x;
  const int tid = threadIdx.x, lane = tid & 63, wid = tid >> 6;
  __shared__ float red[4];

  float pm = (tid < 250) ? pmax[row * 256 + tid] : -INFINITY;
  float ps = (tid < 250) ? psum[row * 256 + tid] : 0.f;

  float m = pm;
  #pragma unroll
  for (int off = 32; off > 0; off >>= 1) m = fmaxf(m, __shfl_xor(m, off));
  if (lane == 0) red[wid] = m;
  __syncthreads();
  m = fmaxf(fmaxf(red[0], red[1]), fmaxf(red[2], red[3]));
  __syncthreads();

  float s = (tid < 250) ? ps * __expf(pm - m) : 0.f;
  #pragma unroll
  for (int off = 32; off > 0; off >>= 1) s += __shfl_xor(s, off);
  if (lane == 0) red[wid] = s;
  __syncthreads();
  s = red[0] + red[1] + red[2] + red[3];
  const float lse = m + logf(s);

  float4* p4 = (float4*)(C + row * (size_t)V_);
  for (int i = tid; i < 8000; i += 256) {
    float4 v = p4[i];
    v.x -= lse; v.y -= lse; v.z -= lse; v.w -= lse;
    p4[i] = v;
  }
}

extern "C" void kernel_launch(void* const* d_in, const int* in_sizes, int n_in,
                              void* d_out, int out_size, void* d_ws, size_t ws_size,
                              hipStream_t stream) {
  const int*   dst  = (const int*)d_in[0];
  const float* E    = (const float*)d_in[1];
  const float* Wih  = (const float*)d_in[2];
  const float* Whh  = (const float*)d_in[3];
  const float* bih  = (const float*)d_in[4];
  const float* bhh  = (const float*)d_in[5];
  const float* h0   = (const float*)d_in[6];
  const float* c0   = (const float*)d_in[7];
  const float* out0 = (const float*)d_in[8];
  float* C = (float*)d_out;

  char* ws = (char*)d_ws;
  unsigned short* Ebf   = (unsigned short*)(ws);                      // 32.77 MB
  unsigned short* preA2 = (unsigned short*)(ws + (size_t)33554432);   // 16.78 MB
  unsigned short* Wrs   = (unsigned short*)(ws + (size_t)50331648);   // 2.10 MB
  unsigned short* embbf = (unsigned short*)(ws + (size_t)52428800);   // pre-phase
  float*          pmax  = (float*)(ws + (size_t)52428800);            // post-phase 4.19 MB
  unsigned short* W1bf  = (unsigned short*)(ws + (size_t)56623104);   // pre-phase
  float*          psum  = (float*)(ws + (size_t)56623104);            // post-phase 4.19 MB
  unsigned short* Abf   = (unsigned short*)(ws + (size_t)60817408);   // 4.19 MB
  unsigned short* hb0   = (unsigned short*)(ws + (size_t)65011712);   // 32 KB
  unsigned short* hb1   = (unsigned short*)(ws + (size_t)65044480);   // 32 KB
  unsigned int*   bar   = (unsigned int*)(ws + (size_t)65077248);     // 256 B

  hipMemsetAsync(bar, 0, 256, stream);

  // --- precompute ---
  embed_bf_kernel<<<dim3(T_ * B_), dim3(64), 0, stream>>>(dst, E, embbf);
  cvt_kernel<<<dim3(2048), dim3(256), 0, stream>>>(E, Ebf, V_ * D_ / 4);
  cvt_w1_kernel<<<dim3(256), dim3(256), 0, stream>>>(Wih, W1bf, 2048 * 512 / 4);
  wr_prep_swz_kernel<<<dim3(256), dim3(256), 0, stream>>>(Wih, Whh, Wrs, 2048 * 512 / 4);

  gemm_pre_kernel<<<dim3(2048 / 128, 4096 / 128), dim3(256), 0, stream>>>(embbf, W1bf, bih, bhh, preA2);
  delta0_kernel<<<dim3(2048), dim3(256), 0, stream>>>(Wih, out0, h0, preA2);
  cvt_kernel<<<dim3(16), dim3(256), 0, stream>>>(h0, hb0, B_ * H_ / 4);

  // --- full recurrence, one launch ---
  lstm_persist_kernel<<<dim3(64), dim3(256), 0, stream>>>(Wrs, preA2, c0, hb0, hb1, Abf, bar);

  // --- projection + fused softmax partials ---
  gemm_bres_kernel<<<dim3(250), dim3(512), 0, stream>>>(Abf, Ebf, C, pmax, psum);
  softmax_finish_kernel<<<dim3(B_ * T_), dim3(256), 0, stream>>>(C, pmax, psum);
}